// Round 6
// baseline (1479.537 us; speedup 1.0000x reference)
//
#include <hip/hip_runtime.h>
#include <stdint.h>

#define HIDDEN 512
#define EMBED  256
#define VTGT   50257
#define TLEN   512
#define GATE3  1536
#define REC_B  16
#define GEMM_B 120
#define NBLK   (REC_B + GEMM_B)
#define NJT    197          // ceil(50257/256) j-tiles of 256

typedef float f32x4 __attribute__((ext_vector_type(4)));
typedef unsigned int u32;
typedef unsigned int u32x2 __attribute__((ext_vector_type(2)));
typedef unsigned int u32x4 __attribute__((ext_vector_type(4)));

__device__ __forceinline__ unsigned short f2bf(float f) {
  union { float f; unsigned u; } v; v.f = f;
  unsigned u = v.u;
  unsigned r = (u + 0x7FFFu + ((u >> 16) & 1u)) >> 16;
  return (unsigned short)r;
}

__device__ __forceinline__ float sigm(float x) {
  return 1.f / (1.f + __expf(-x));
}
__device__ __forceinline__ float fast_tanh(float x) {
  return 1.f - 2.f / (__expf(2.f * x) + 1.f);
}

// single coherent dword poll (one RTT per sample)
__device__ __forceinline__ u32 cpoll(const u32* p) {
  u32 v;
  asm volatile("global_load_dword %0, %1, off sc0 sc1\n\ts_waitcnt vmcnt(0)"
               : "=v"(v) : "v"(p) : "memory");
  return v;
}
// 4x dwordx4 coherent, single flight
__device__ __forceinline__ void cload4x4(const u32* p, u32x4& a, u32x4& b,
                                         u32x4& c, u32x4& d) {
  asm volatile(
      "global_load_dwordx4 %0, %4, off sc0 sc1\n\t"
      "global_load_dwordx4 %1, %4, off offset:16 sc0 sc1\n\t"
      "global_load_dwordx4 %2, %4, off offset:32 sc0 sc1\n\t"
      "global_load_dwordx4 %3, %4, off offset:48 sc0 sc1\n\t"
      "s_waitcnt vmcnt(0)"
      : "=v"(a), "=v"(b), "=v"(c), "=v"(d) : "v"(p) : "memory");
}
__device__ __forceinline__ void cstore2(u32* p, u32x2 v) {
  asm volatile("global_store_dwordx2 %0, %1, off sc0 sc1" :: "v"(p), "v"(v) : "memory");
}

// ---------- encoder: gi = Wih_e @ x_last + bih_e ----------
__global__ void kenc1(const int* source, const float* emb_e, const float* Wih_e,
                      const float* bih_e, float* genc) {
  __shared__ float xs[EMBED];
  int tid = threadIdx.x;
  int tok = source[511];
  if (tid < EMBED) xs[tid] = emb_e[(size_t)tok * EMBED + tid];
  __syncthreads();
  int j = blockIdx.x * 256 + tid;
  const float* w = Wih_e + (size_t)j * EMBED;
  float acc = bih_e[j];
  for (int k = 0; k < EMBED; k += 4) {
    float4 wv = *(const float4*)(w + k);
    acc += wv.x * xs[k] + wv.y * xs[k + 1] + wv.z * xs[k + 2] + wv.w * xs[k + 3];
  }
  genc[j] = acc;
}

// ---------- encoder gates: write tagged h_0 into hs slot 0 ----------
__global__ void kenc2(const float* genc, const float* bhh_e, u32* hs) {
  int e = threadIdx.x; // 512 threads
  float r = sigm(genc[e] + bhh_e[e]);
  float z = sigm(genc[e + 512] + bhh_e[e + 512]);
  float n = tanhf(genc[e + 1024] + r * bhh_e[e + 1024]);
  float h = (1.f - z) * n;
  hs[e] = (__float_as_uint(h) & ~511u) | 256u;  // tag(0) = 256
}

// ---------- GI[t][j] = Wih_d @ relu(emb_d[tok_t]) + bih_d ----------
__global__ __launch_bounds__(256) void kgi(const int* target, const float* emb_d,
                                           const float* Wih_d, const float* bih_d,
                                           float* GI) {
  __shared__ float Xs[32][EMBED];
  int tid = threadIdx.x;
  int j0 = blockIdx.x * 128;
  int t0 = blockIdx.y * 32;
  for (int idx = tid; idx < 32 * EMBED; idx += 256) {
    int tt = idx >> 8, c = idx & 255;
    int t = t0 + tt;
    int tok = (t == 0) ? 0 : target[t - 1];
    float v = emb_d[(size_t)tok * EMBED + c];
    Xs[tt][c] = v > 0.f ? v : 0.f;
  }
  __syncthreads();
  int jl = tid & 127, tg = tid >> 7;
  int j = j0 + jl;
  const float* w = Wih_d + (size_t)j * EMBED;
  float acc[16];
#pragma unroll
  for (int i = 0; i < 16; ++i) acc[i] = 0.f;
  for (int k = 0; k < EMBED; k += 4) {
    float4 wv = *(const float4*)(w + k);
#pragma unroll
    for (int i = 0; i < 16; ++i) {
      int tl = tg * 16 + i;
      acc[i] += wv.x * Xs[tl][k] + wv.y * Xs[tl][k + 1] +
                wv.z * Xs[tl][k + 2] + wv.w * Xs[tl][k + 3];
    }
  }
  float b = bih_d[j];
#pragma unroll
  for (int i = 0; i < 16; ++i) {
    int t = t0 + tg * 16 + i;
    GI[(size_t)t * GATE3 + j] = acc[i] + b;
  }
}

// ---------- recurrence path: 16 blocks x 1024 thr, k-split 32 (48 weight VGPRs) ----------
__device__ void rec_path(int bid, const float* Whh, const float* bhh,
                         const float* GI, u32* hs, char* SM) {
  int tid = threadIdx.x;
  int p = tid & 31;            // k-slice 0..31 (16 values each)
  int r = tid >> 5;            // e-row 0..31
  int e = bid * 32 + r;
  int k0 = p * 16;
  float* hbuf = (float*)SM;    // [2][576] padded stride 36 per 32
  float wr[16], wz[16], wn[16];
  {
    const float* Wr = Whh + (size_t)e * HIDDEN + k0;
    const float* Wz = Whh + (size_t)(e + 512) * HIDDEN + k0;
    const float* Wn = Whh + (size_t)(e + 1024) * HIDDEN + k0;
#pragma unroll
    for (int i = 0; i < 16; i += 4) {
      *(float4*)&wr[i] = *(const float4*)(Wr + i);
      *(float4*)&wz[i] = *(const float4*)(Wz + i);
      *(float4*)&wn[i] = *(const float4*)(Wn + i);
    }
  }
  float br = bhh[e], bz = bhh[e + 512], bn = bhh[e + 1024];
  float hold = 0.f;
  if (p == 0) hold = __uint_as_float(hs[e] & ~511u);  // h^0[e], register-resident
  __builtin_amdgcn_s_setprio(1);
  int pslot = ((tid >> 5) * 36) + (tid & 31);         // poll write slot (tid<512)
  int dbase = (p >> 1) * 36 + (p & 1) * 16;           // dot read base
  for (int t = 0; t < TLEN; ++t) {
    int par = t & 1;
    float gie = 0.f, giz = 0.f, gin = 0.f;
    if (p == 0) {
      const float* git = GI + (size_t)t * GATE3;
      gie = git[e]; giz = git[e + 512]; gin = git[e + 1024];
    }
    if (tid < 512) {           // waves 0..7 poll one dword each
      const u32* src = hs + (size_t)t * HIDDEN + tid;
      u32 want = 256u + ((u32)t & 255u);
      u32 v;
      do { v = cpoll(src); } while ((v & 511u) != want);
      hbuf[par * 576 + pslot] = __uint_as_float(v & ~511u);
    }
    __syncthreads();
    const float* hp = hbuf + par * 576 + dbase;
    float pr = 0.f, pz = 0.f, pn = 0.f;
#pragma unroll
    for (int i = 0; i < 16; i += 4) {
      float4 hv = *(const float4*)(hp + i);
      pr += wr[i] * hv.x + wr[i + 1] * hv.y + wr[i + 2] * hv.z + wr[i + 3] * hv.w;
      pz += wz[i] * hv.x + wz[i + 1] * hv.y + wz[i + 2] * hv.z + wz[i + 3] * hv.w;
      pn += wn[i] * hv.x + wn[i + 1] * hv.y + wn[i + 2] * hv.z + wn[i + 3] * hv.w;
    }
#pragma unroll
    for (int m = 1; m < 32; m <<= 1) {
      pr += __shfl_xor(pr, m);
      pz += __shfl_xor(pz, m);
      pn += __shfl_xor(pn, m);
    }
    u32 pk = 0;
    if (p == 0) {
      float rg = sigm(gie + pr + br);
      float z  = sigm(giz + pz + bz);
      float n  = fast_tanh(gin + rg * (pn + bn));
      float hnew = (1.f - z) * n + z * hold;
      hold = hnew;
      pk = (__float_as_uint(hnew) & ~511u) | (256u + ((u32)(t + 1) & 255u));
    }
    u32 other = __shfl(pk, 32);        // lane32's pk -> lane0
    if ((tid & 63) == 0) {
      u32x2 o; o[0] = pk; o[1] = other;
      cstore2(hs + (size_t)(t + 1) * HIDDEN + bid * 32 + (tid >> 6) * 2, o);
    }
    // no tail barrier: next step's pollers write the other parity
  }
}

// ---------- GEMM path: 120 blocks x 1024 thr, 256-wide j-tiles, row-sum fused ----------
__device__ void gemm_path(int g, const u32* hs, const float* Wout,
                          const float* bout, float* rs, float* out, char* SM) {
  unsigned short* As = (unsigned short*)SM;       // [64][520] bf16
  float* rsum = (float*)(SM + 64 * 520 * 2);      // [64]
  int tid = threadIdx.x;
  int w = tid >> 6, lane = tid & 63;
  int jl = lane & 15, kq = lane >> 4;
  int srow = tid >> 4, scg = tid & 15;            // stage: row 0..63, 32-dword group
  if (tid < 64) rsum[tid] = 0.f;
  for (int t0i = 0; t0i < 8; ++t0i) {
    int t0 = t0i * 64;
    if (tid == 0) {  // sleep-throttled sentinel hint: slot t0+64, element 256
      const u32* hp = hs + (size_t)(t0 + 64) * HIDDEN + 256;
      u32 hw = 256u + ((u32)(t0 + 64) & 255u);
      while ((cpoll(hp) & 511u) != hw) __builtin_amdgcn_s_sleep(16);
    }
    __syncthreads();
    // stage A tile: rows t0..t0+63 from tagged hs slots t0+1..t0+64
    int slot = t0 + srow + 1;
    u32 want = 256u + ((u32)slot & 255u);
#pragma unroll
    for (int b = 0; b < 2; ++b) {
      const u32* sp = hs + (size_t)slot * HIDDEN + scg * 32 + b * 16;
      u32x4 c0, c1, c2, c3;
      for (;;) {
        cload4x4(sp, c0, c1, c2, c3);
        u32 bad = 0;
#pragma unroll
        for (int q = 0; q < 4; ++q)
          bad |= (c0[q] ^ want) | (c1[q] ^ want) | (c2[q] ^ want) | (c3[q] ^ want);
        if (!(bad & 511u)) break;
      }
      u32 dw[8];
#pragma unroll
      for (int q = 0; q < 4; ++q) {
        u32x4 cq = (q == 0) ? c0 : (q == 1) ? c1 : (q == 2) ? c2 : c3;
        float f0 = __uint_as_float(cq[0] & ~511u);
        float f1 = __uint_as_float(cq[1] & ~511u);
        float f2 = __uint_as_float(cq[2] & ~511u);
        float f3 = __uint_as_float(cq[3] & ~511u);
        dw[q * 2]     = (u32)f2bf(f0) | ((u32)f2bf(f1) << 16);
        dw[q * 2 + 1] = (u32)f2bf(f2) | ((u32)f2bf(f3) << 16);
      }
      *(u32x4*)&As[srow * 520 + scg * 32 + b * 16]     = *(u32x4*)&dw[0];
      *(u32x4*)&As[srow * 520 + scg * 32 + b * 16 + 8] = *(u32x4*)&dw[4];
    }
    __syncthreads();
    for (int jt = g; jt < NJT; jt += GEMM_B) {
      int j = jt * 256 + w * 16 + jl;
      int jc = j < VTGT ? j : VTGT - 1;
      const float* Bp = Wout + (size_t)jc * HIDDEN + kq * 8;
      f32x4 acc[4];
#pragma unroll
      for (int i = 0; i < 4; ++i) acc[i] = (f32x4)(0.f);
#pragma unroll
      for (int ks = 0; ks < 16; ++ks) {
        float4 b0 = *(const float4*)(Bp + ks * 32);
        float4 b1 = *(const float4*)(Bp + ks * 32 + 4);
        u32x4 bf;
        bf[0] = (u32)f2bf(b0.x) | ((u32)f2bf(b0.y) << 16);
        bf[1] = (u32)f2bf(b0.z) | ((u32)f2bf(b0.w) << 16);
        bf[2] = (u32)f2bf(b1.x) | ((u32)f2bf(b1.y) << 16);
        bf[3] = (u32)f2bf(b1.z) | ((u32)f2bf(b1.w) << 16);
#pragma unroll
        for (int tq = 0; tq < 4; ++tq) {
          u32x4 af = *(const u32x4*)&As[(tq * 16 + jl) * 520 + ks * 32 + kq * 8];
          asm volatile("v_mfma_f32_16x16x32_bf16 %0, %1, %2, %0"
                       : "+v"(acc[tq]) : "v"(af), "v"(bf));
        }
      }
      asm volatile("s_nop 7\n\ts_nop 7\n\ts_nop 7" ::);
      bool jok = j < VTGT;
      float bj = jok ? bout[j] : 0.f;
#pragma unroll
      for (int tq = 0; tq < 4; ++tq) {
#pragma unroll
        for (int rr = 0; rr < 4; ++rr) {
          int t = t0 + tq * 16 + kq * 4 + rr;  // D: row=(lane>>4)*4+reg, col=lane&15
          float lg = acc[tq][rr] + bj;
          if (jok) out[(size_t)t * VTGT + j] = lg;
          float ex = jok ? __expf(lg) : 0.f;
#pragma unroll
          for (int m = 1; m < 16; m <<= 1) ex += __shfl_xor(ex, m);
          if (jl == 0) atomicAdd(&rsum[tq * 16 + kq * 4 + rr], ex);
        }
      }
    }
    __syncthreads();  // all As/rsum updates done
    if (tid < 64) {
      atomicAdd(rs + t0 + tid, rsum[tid]);
      rsum[tid] = 0.f;
    }
  }
}

// ---------- fused mega-kernel ----------
__global__ __launch_bounds__(1024, 4) void kmain(const float* Whh, const float* bhh,
                                                 const float* GI, u32* hs,
                                                 const float* Wout, const float* bout,
                                                 float* rs, float* out) {
  __shared__ __align__(16) char SM[64 * 520 * 2 + 256];  // As + rsum / hbuf union
  int bid = blockIdx.x;
  if (bid < REC_B) rec_path(bid, Whh, bhh, GI, hs, SM);
  else gemm_path(bid - REC_B, hs, Wout, bout, rs, out, SM);
}

// ---------- logp = logits - log(rowsum), single pass ----------
__global__ __launch_bounds__(1024) void klsub(float* out, const float* rs) {
  int t = blockIdx.x;
  float l = logf(rs[t]);
  float* row = out + (size_t)t * VTGT;
  for (int jj = threadIdx.x; jj < VTGT; jj += 1024) row[jj] -= l;
}

extern "C" void kernel_launch(void* const* d_in, const int* in_sizes, int n_in,
                              void* d_out, int out_size, void* d_ws, size_t ws_size,
                              hipStream_t stream) {
  const int*   source = (const int*)d_in[0];
  const int*   target = (const int*)d_in[1];
  const float* emb_e  = (const float*)d_in[2];
  const float* Wih_e  = (const float*)d_in[3];
  // d_in[4] = Whh_e: unused (h0 == 0)
  const float* bih_e  = (const float*)d_in[5];
  const float* bhh_e  = (const float*)d_in[6];
  const float* emb_d  = (const float*)d_in[7];
  const float* Wih_d  = (const float*)d_in[8];
  const float* Whh_d  = (const float*)d_in[9];
  const float* bih_d  = (const float*)d_in[10];
  const float* bhh_d  = (const float*)d_in[11];
  const float* Wout   = (const float*)d_in[12];
  const float* bout   = (const float*)d_in[13];
  float* out = (float*)d_out;
  char* ws = (char*)d_ws;

  // ws layout (bytes), 256-aligned
  float* GI   = (float*)(ws + 0);           // 3,145,728
  u32*   hs   = (u32*)(ws + 3145728);       // 1,050,624 (513 x 512 tagged f32)
  float* rs   = (float*)(ws + 4196352);     //     2,048 (row sum-exp)
  float* genc = (float*)(ws + 4198400);     //     6,144
  // total ws use ~4.2 MB

  hipMemsetAsync(hs, 0, 1050624 + 2048, stream);  // hs tags + rs
  kenc1<<<6, 256, 0, stream>>>(source, emb_e, Wih_e, bih_e, genc);
  kenc2<<<1, 512, 0, stream>>>(genc, bhh_e, hs);
  kgi<<<dim3(12, 16), 256, 0, stream>>>(target, emb_d, Wih_d, bih_d, GI);
  kmain<<<NBLK, 1024, 0, stream>>>(Whh_d, bhh_d, GI, hs, Wout, bout, rs, out);
  klsub<<<512, 1024, 0, stream>>>(out, rs);
}

// Round 7
// 876.763 us; speedup vs baseline: 1.6875x; 1.6875x over previous
//
#include <hip/hip_runtime.h>
#include <stdint.h>

#define HIDDEN 512
#define EMBED  256
#define VTGT   50257
#define TLEN   512
#define GATE3  1536
#define REC_B  16
#define GEMM_B 224
#define NBLK   (REC_B + GEMM_B)
#define NJT    ((VTGT + 127) / 128)   // 393 j-tiles of 128

typedef float f32x4 __attribute__((ext_vector_type(4)));
typedef unsigned int u32;
typedef unsigned int u32x2 __attribute__((ext_vector_type(2)));
typedef unsigned int u32x4 __attribute__((ext_vector_type(4)));

__device__ __forceinline__ unsigned short f2bf(float f) {
  union { float f; unsigned u; } v; v.f = f;
  unsigned u = v.u;
  unsigned r = (u + 0x7FFFu + ((u >> 16) & 1u)) >> 16;
  return (unsigned short)r;
}

__device__ __forceinline__ float sigm(float x) {
  return __builtin_amdgcn_rcpf(1.f + __expf(-x));
}
__device__ __forceinline__ float fast_tanh(float x) {
  return 1.f - 2.f * __builtin_amdgcn_rcpf(__expf(2.f * x) + 1.f);
}

// single coherent dword poll (one RTT per sample)
__device__ __forceinline__ u32 cpoll(const u32* p) {
  u32 v;
  asm volatile("global_load_dword %0, %1, off sc0 sc1\n\ts_waitcnt vmcnt(0)"
               : "=v"(v) : "v"(p) : "memory");
  return v;
}
// 4x dwordx4 coherent, single flight
__device__ __forceinline__ void cload4x4(const u32* p, u32x4& a, u32x4& b,
                                         u32x4& c, u32x4& d) {
  asm volatile(
      "global_load_dwordx4 %0, %4, off sc0 sc1\n\t"
      "global_load_dwordx4 %1, %4, off offset:16 sc0 sc1\n\t"
      "global_load_dwordx4 %2, %4, off offset:32 sc0 sc1\n\t"
      "global_load_dwordx4 %3, %4, off offset:48 sc0 sc1\n\t"
      "s_waitcnt vmcnt(0)"
      : "=v"(a), "=v"(b), "=v"(c), "=v"(d) : "v"(p) : "memory");
}
// 2x dwordx4 coherent at p0 and p1, single flight
__device__ __forceinline__ void cload2(const u32* p0, const u32* p1,
                                       u32x4& a, u32x4& b) {
  asm volatile(
      "global_load_dwordx4 %0, %2, off sc0 sc1\n\t"
      "global_load_dwordx4 %1, %3, off sc0 sc1\n\t"
      "s_waitcnt vmcnt(0)"
      : "=v"(a), "=v"(b) : "v"(p0), "v"(p1) : "memory");
}
__device__ __forceinline__ void cstore(u32* p, u32 v) {
  asm volatile("global_store_dword %0, %1, off sc0 sc1" :: "v"(p), "v"(v) : "memory");
}

// ---------- encoder: gi = Wih_e @ x_last + bih_e ----------
__global__ void kenc1(const int* source, const float* emb_e, const float* Wih_e,
                      const float* bih_e, float* genc) {
  __shared__ float xs[EMBED];
  int tid = threadIdx.x;
  int tok = source[511];
  if (tid < EMBED) xs[tid] = emb_e[(size_t)tok * EMBED + tid];
  __syncthreads();
  int j = blockIdx.x * 256 + tid;
  const float* w = Wih_e + (size_t)j * EMBED;
  float acc = bih_e[j];
  for (int k = 0; k < EMBED; k += 4) {
    float4 wv = *(const float4*)(w + k);
    acc += wv.x * xs[k] + wv.y * xs[k + 1] + wv.z * xs[k + 2] + wv.w * xs[k + 3];
  }
  genc[j] = acc;
}

// ---------- encoder gates: write tagged h_0 into hs slot 0 ----------
__global__ void kenc2(const float* genc, const float* bhh_e, u32* hs) {
  int e = threadIdx.x; // 512 threads
  float r = sigm(genc[e] + bhh_e[e]);
  float z = sigm(genc[e + 512] + bhh_e[e + 512]);
  float n = tanhf(genc[e + 1024] + r * bhh_e[e + 1024]);
  float h = (1.f - z) * n;
  hs[e] = (__float_as_uint(h) & ~511u) | 256u;  // tag(0) = 256
}

// ---------- GI[t][j] = Wih_d @ relu(emb_d[tok_t]) + bih_d ----------
__global__ __launch_bounds__(256) void kgi(const int* target, const float* emb_d,
                                           const float* Wih_d, const float* bih_d,
                                           float* GI) {
  __shared__ float Xs[32][EMBED];
  int tid = threadIdx.x;
  int j0 = blockIdx.x * 128;
  int t0 = blockIdx.y * 32;
  for (int idx = tid; idx < 32 * EMBED; idx += 256) {
    int tt = idx >> 8, c = idx & 255;
    int t = t0 + tt;
    int tok = (t == 0) ? 0 : target[t - 1];
    float v = emb_d[(size_t)tok * EMBED + c];
    Xs[tt][c] = v > 0.f ? v : 0.f;
  }
  __syncthreads();
  int jl = tid & 127, tg = tid >> 7;
  int j = j0 + jl;
  const float* w = Wih_d + (size_t)j * EMBED;
  float acc[16];
#pragma unroll
  for (int i = 0; i < 16; ++i) acc[i] = 0.f;
  for (int k = 0; k < EMBED; k += 4) {
    float4 wv = *(const float4*)(w + k);
#pragma unroll
    for (int i = 0; i < 16; ++i) {
      int tl = tg * 16 + i;
      acc[i] += wv.x * Xs[tl][k] + wv.y * Xs[tl][k + 1] +
                wv.z * Xs[tl][k + 2] + wv.w * Xs[tl][k + 3];
    }
  }
  float b = bih_d[j];
#pragma unroll
  for (int i = 0; i < 16; ++i) {
    int t = t0 + tg * 16 + i;
    GI[(size_t)t * GATE3 + j] = acc[i] + b;
  }
}

// ---------- recurrence: 16 blocks x 512 thr, VGPR-resident weights ----------
__device__ void rec_path(int bid, const float* Whh, const float* bhh,
                         const float* GI, u32* hs, u32* stepv, char* SM) {
  int tid = threadIdx.x;
  int p = tid & 15, r = tid >> 4;     // k-slice 0..15, row 0..31
  int e = bid * 32 + r;
  int k0 = p * 32;
  float* hbuf = (float*)SM;           // [2][576] padded stride 36 per 32
  // weights as vector-typed arrays, constant indices only -> VGPR-resident
  f32x4 wr4[8], wz4[8], wn4[8];
  {
    const f32x4* Wr = (const f32x4*)(Whh + (size_t)e * HIDDEN + k0);
    const f32x4* Wz = (const f32x4*)(Whh + (size_t)(e + 512) * HIDDEN + k0);
    const f32x4* Wn = (const f32x4*)(Whh + (size_t)(e + 1024) * HIDDEN + k0);
#pragma unroll
    for (int i = 0; i < 8; ++i) { wr4[i] = Wr[i]; wz4[i] = Wz[i]; wn4[i] = Wn[i]; }
  }
  float br = bhh[e], bz = bhh[e + 512], bn = bhh[e + 1024];
  float hold = __uint_as_float(hs[e] & ~511u);   // h^0[e], register-resident
  __builtin_amdgcn_s_setprio(1);
  // wave-0 poll geometry: lane handles dwords d0=tid*4 (.. +3) and d0+256
  int d0 = tid * 4;
  int i0 = ((d0 >> 5) * 36) + (d0 & 31);
  int i1 = (((d0 + 256) >> 5) * 36) + (d0 & 31);
  for (int t = 0; t < TLEN; ++t) {
    int par = t & 1;
    float gie = 0.f, giz = 0.f, gin = 0.f;
    if (p == 0) {
      const float* git = GI + (size_t)t * GATE3;
      gie = git[e]; giz = git[e + 512]; gin = git[e + 1024];
    }
    if (tid < 64) {
      const u32* s0 = hs + (size_t)t * HIDDEN + d0;
      const u32* s1 = s0 + 256;
      u32 want = 256u + ((u32)t & 255u);
      u32x4 a, b;
      for (;;) {
        cload2(s0, s1, a, b);
        u32 bad = 0;
#pragma unroll
        for (int q = 0; q < 4; ++q) bad |= (a[q] ^ want) | (b[q] ^ want);
        if (!__any((bad & 511u) != 0u)) break;
      }
      f32x4 fa, fb;
#pragma unroll
      for (int q = 0; q < 4; ++q) {
        fa[q] = __uint_as_float(a[q] & ~511u);
        fb[q] = __uint_as_float(b[q] & ~511u);
      }
      *(f32x4*)&hbuf[par * 576 + i0] = fa;
      *(f32x4*)&hbuf[par * 576 + i1] = fb;
    }
    __syncthreads();
    if (bid == 0 && tid == 0) cstore(stepv, (u32)t);  // slot t globally visible
    const f32x4* hp4 = (const f32x4*)(hbuf + par * 576 + p * 36);
    float pr = 0.f, pz = 0.f, pn = 0.f;
#pragma unroll
    for (int i = 0; i < 8; ++i) {
      f32x4 hv = hp4[i];
      pr += wr4[i][0] * hv[0] + wr4[i][1] * hv[1] + wr4[i][2] * hv[2] + wr4[i][3] * hv[3];
      pz += wz4[i][0] * hv[0] + wz4[i][1] * hv[1] + wz4[i][2] * hv[2] + wz4[i][3] * hv[3];
      pn += wn4[i][0] * hv[0] + wn4[i][1] * hv[1] + wn4[i][2] * hv[2] + wn4[i][3] * hv[3];
    }
#pragma unroll
    for (int m = 1; m < 16; m <<= 1) {
      pr += __shfl_xor(pr, m);
      pz += __shfl_xor(pz, m);
      pn += __shfl_xor(pn, m);
    }
    if (p == 0) {
      float rg = sigm(gie + pr + br);
      float z  = sigm(giz + pz + bz);
      float n  = fast_tanh(gin + rg * (pn + bn));
      float hnew = (1.f - z) * n + z * hold;
      hold = hnew;
      u32 pk = (__float_as_uint(hnew) & ~511u) | (256u + ((u32)(t + 1) & 255u));
      cstore(hs + (size_t)(t + 1) * HIDDEN + e, pk);
    }
    // no tail barrier: next step's poller writes the other hbuf parity
  }
  if (bid == 0 && tid < 64) {  // confirm final slot 512 -> stepv = 512
    const u32* s0 = hs + (size_t)TLEN * HIDDEN + d0;
    const u32* s1 = s0 + 256;
    u32 want = 256u + ((u32)TLEN & 255u);
    u32x4 a, b;
    for (;;) {
      cload2(s0, s1, a, b);
      u32 bad = 0;
#pragma unroll
      for (int q = 0; q < 4; ++q) bad |= (a[q] ^ want) | (b[q] ^ want);
      if (!__any((bad & 511u) != 0u)) break;
    }
    if (tid == 0) cstore(stepv, (u32)TLEN);
  }
}

// ---------- GEMM path: tag-verified A staging, on-the-fly bf16 B, fused row-sum ----------
__device__ void gemm_path(int g, const u32* hs, u32* stepv, const float* Wout,
                          const float* bout, float* rs, float* out, char* SM) {
  unsigned short* As = (unsigned short*)SM;       // [64][520] bf16
  float* rsum = (float*)(SM + 64 * 520 * 2);      // [64]
  int tid = threadIdx.x;
  int w = tid >> 6, lane = tid & 63;
  int jl = lane & 15, kq = lane >> 4;
  int srow = tid >> 3, scg = tid & 7;             // stage: row 0..63, 64-dword group
  if (tid < 64) rsum[tid] = 0.f;
  for (int t0i = 0; t0i < 8; ++t0i) {
    int t0 = t0i * 64;
    if (tid == 0) {  // sleep-throttled progress hint (tags stay authoritative)
      while ((int)cpoll(stepv) < t0 + 64) __builtin_amdgcn_s_sleep(16);
    }
    __syncthreads();
    // stage A tile: rows t0..t0+63 from tagged hs slots t0+1..t0+64
    int slot = t0 + srow + 1;
    u32 want = 256u + ((u32)slot & 255u);
    const u32* sbase = hs + (size_t)slot * HIDDEN + scg * 64;
#pragma unroll
    for (int b = 0; b < 4; ++b) {
      const u32* sp = sbase + b * 16;
      u32x4 c0, c1, c2, c3;
      for (;;) {
        cload4x4(sp, c0, c1, c2, c3);
        u32 bad = 0;
#pragma unroll
        for (int q = 0; q < 4; ++q)
          bad |= (c0[q] ^ want) | (c1[q] ^ want) | (c2[q] ^ want) | (c3[q] ^ want);
        if (!(bad & 511u)) break;
      }
      u32 dw[8];
#pragma unroll
      for (int q = 0; q < 4; ++q) {
        u32x4 cq = (q == 0) ? c0 : (q == 1) ? c1 : (q == 2) ? c2 : c3;
        float f0 = __uint_as_float(cq[0] & ~511u);
        float f1 = __uint_as_float(cq[1] & ~511u);
        float f2 = __uint_as_float(cq[2] & ~511u);
        float f3 = __uint_as_float(cq[3] & ~511u);
        dw[q * 2]     = (u32)f2bf(f0) | ((u32)f2bf(f1) << 16);
        dw[q * 2 + 1] = (u32)f2bf(f2) | ((u32)f2bf(f3) << 16);
      }
      *(u32x4*)&As[srow * 520 + scg * 64 + b * 16]     = *(u32x4*)&dw[0];
      *(u32x4*)&As[srow * 520 + scg * 64 + b * 16 + 8] = *(u32x4*)&dw[4];
    }
    __syncthreads();
    for (int jt = g; jt < NJT; jt += GEMM_B) {
      int j = jt * 128 + w * 16 + jl;
      int jc = j < VTGT ? j : VTGT - 1;
      const float* Bp = Wout + (size_t)jc * HIDDEN + kq * 8;
      f32x4 acc[4];
#pragma unroll
      for (int i = 0; i < 4; ++i) acc[i] = (f32x4)(0.f);
#pragma unroll
      for (int ks = 0; ks < 16; ++ks) {
        float4 b0 = *(const float4*)(Bp + ks * 32);
        float4 b1 = *(const float4*)(Bp + ks * 32 + 4);
        u32x4 bf;
        bf[0] = (u32)f2bf(b0.x) | ((u32)f2bf(b0.y) << 16);
        bf[1] = (u32)f2bf(b0.z) | ((u32)f2bf(b0.w) << 16);
        bf[2] = (u32)f2bf(b1.x) | ((u32)f2bf(b1.y) << 16);
        bf[3] = (u32)f2bf(b1.z) | ((u32)f2bf(b1.w) << 16);
#pragma unroll
        for (int tq = 0; tq < 4; ++tq) {
          u32x4 af = *(const u32x4*)&As[(tq * 16 + jl) * 520 + ks * 32 + kq * 8];
          asm volatile("v_mfma_f32_16x16x32_bf16 %0, %1, %2, %0"
                       : "+v"(acc[tq]) : "v"(af), "v"(bf));
        }
      }
      asm volatile("s_nop 7\n\ts_nop 7\n\ts_nop 7" ::);
      bool jok = j < VTGT;
      float bj = jok ? bout[j] : 0.f;
#pragma unroll
      for (int tq = 0; tq < 4; ++tq) {
#pragma unroll
        for (int rr = 0; rr < 4; ++rr) {
          int t = t0 + tq * 16 + kq * 4 + rr;  // D: row=(lane>>4)*4+reg, col=lane&15
          float lg = acc[tq][rr] + bj;
          if (jok) out[(size_t)t * VTGT + j] = lg;
          float ex = jok ? __expf(lg) : 0.f;
#pragma unroll
          for (int m = 1; m < 16; m <<= 1) ex += __shfl_xor(ex, m);
          if (jl == 0) atomicAdd(&rsum[tq * 16 + kq * 4 + rr], ex);
        }
      }
    }
    __syncthreads();  // all As reads + rsum adds done
    if (tid < 64) {
      atomicAdd(rs + t0 + tid, rsum[tid]);
      rsum[tid] = 0.f;
    }
  }
}

// ---------- fused mega-kernel: 16 rec blocks + 224 persistent GEMM blocks ----------
__global__ __launch_bounds__(512) void kmain(const float* Whh, const float* bhh,
                                             const float* GI, u32* hs, u32* stepv,
                                             const float* Wout, const float* bout,
                                             float* rs, float* out) {
  __shared__ __align__(16) char SM[64 * 520 * 2 + 256];  // As+rsum / hbuf union
  int bid = blockIdx.x;
  if (bid < REC_B) rec_path(bid, Whh, bhh, GI, hs, stepv, SM);
  else gemm_path(bid - REC_B, hs, stepv, Wout, bout, rs, out, SM);
}

// ---------- logp = logits - log(rowsum), single pass ----------
__global__ __launch_bounds__(1024) void klsub(float* out, const float* rs) {
  int t = blockIdx.x;
  float l = logf(rs[t]);
  float* row = out + (size_t)t * VTGT;
  for (int jj = threadIdx.x; jj < VTGT; jj += 1024) row[jj] -= l;
}

extern "C" void kernel_launch(void* const* d_in, const int* in_sizes, int n_in,
                              void* d_out, int out_size, void* d_ws, size_t ws_size,
                              hipStream_t stream) {
  const int*   source = (const int*)d_in[0];
  const int*   target = (const int*)d_in[1];
  const float* emb_e  = (const float*)d_in[2];
  const float* Wih_e  = (const float*)d_in[3];
  // d_in[4] = Whh_e: unused (h0 == 0)
  const float* bih_e  = (const float*)d_in[5];
  const float* bhh_e  = (const float*)d_in[6];
  const float* emb_d  = (const float*)d_in[7];
  const float* Wih_d  = (const float*)d_in[8];
  const float* Whh_d  = (const float*)d_in[9];
  const float* bih_d  = (const float*)d_in[10];
  const float* bhh_d  = (const float*)d_in[11];
  const float* Wout   = (const float*)d_in[12];
  const float* bout   = (const float*)d_in[13];
  float* out = (float*)d_out;
  char* ws = (char*)d_ws;

  // ws layout (bytes), 256-aligned
  float* GI    = (float*)(ws + 0);           // 3,145,728
  u32*   hs    = (u32*)(ws + 3145728);       // 1,050,624 (513 x 512 tagged f32)
  u32*   stepv = (u32*)(ws + 4196352);       //       128
  float* rs    = (float*)(ws + 4196480);     //     2,048 (row sum-exp)
  float* genc  = (float*)(ws + 4198528);     //     6,144
  // total ws use ~4.2 MB

  hipMemsetAsync(hs, 0, 1052800, stream);    // hs tags + stepv + rs
  kenc1<<<6, 256, 0, stream>>>(source, emb_e, Wih_e, bih_e, genc);
  kenc2<<<1, 512, 0, stream>>>(genc, bhh_e, hs);
  kgi<<<dim3(12, 16), 256, 0, stream>>>(target, emb_d, Wih_d, bih_d, GI);
  kmain<<<NBLK, 512, 0, stream>>>(Whh_d, bhh_d, GI, hs, stepv, Wout, bout, rs, out);
  klsub<<<512, 1024, 0, stream>>>(out, rs);
}